// Round 3
// baseline (129.455 us; speedup 1.0000x reference)
//
#include <hip/hip_runtime.h>
#include <hip/hip_bf16.h>

// NT-Xent (SimCLR) loss, B=4096, D=256, N=8192, T=0.5.
// loss = [ sum_i log(sum_{j!=i} exp(sim_ij * 2)) - 4 * sum_{i<B} pos_i ] / N
// sim symmetric => row sums computed as column sums of MFMA tiles (per-lane).
//
// Z is stored pre-scaled by sqrt(2*log2(e)) so the MFMA emits sim*2*log2(e)
// directly (epilogue = bare exp2). pos uses the exact fp32 path in normalize.
// No LDS / no barriers in the GEMM: MFMA A-fragments (lane=row, k contiguous)
// are 16B row-major runs of Z, loaded straight from global (L1/L2-resident).

constexpr int BB = 4096;     // batch
constexpr int NN = 8192;     // 2*batch
constexpr int DD = 256;      // feature dim
constexpr int RT = 256;      // r-rows per block
constexpr int CC = 512;      // c-columns per block chunk
constexpr int NRT = NN / RT; // 32 row tiles
constexpr int NCH = NN / CC; // 16 column chunks
constexpr int CSTEPS = CC / 32;

typedef _Float16 half4v __attribute__((ext_vector_type(4)));
typedef _Float16 half8v __attribute__((ext_vector_type(8)));
typedef float floatx16 __attribute__((ext_vector_type(16)));

// sqrt(2*log2(e)) : each side of the dot product carries one factor.
#define SQK 1.69864414f

// ---------------- Kernel 1: normalize rows -> f16 (pre-scaled), pos, zero ----
__global__ __launch_bounds__(256) void nt_normalize(
    const float* __restrict__ zi, const float* __restrict__ zj,
    _Float16* __restrict__ Z, float* __restrict__ posPartial,
    float* __restrict__ rowsum)
{
    const int lane = threadIdx.x & 63;
    const int wave = threadIdx.x >> 6;
    const int i = blockIdx.x * 4 + wave;   // pair index, < BB

    // Zero rowsum (8192 floats) with the first 32 blocks (stream-ordered
    // before simexp, so no race).
    if (blockIdx.x < 32) rowsum[blockIdx.x * 256 + threadIdx.x] = 0.f;

    const float4 a = ((const float4*)(zi + (size_t)i * DD))[lane];
    const float4 b = ((const float4*)(zj + (size_t)i * DD))[lane];

    float ssi = a.x*a.x + a.y*a.y + a.z*a.z + a.w*a.w;
    float ssj = b.x*b.x + b.y*b.y + b.z*b.z + b.w*b.w;
    float dd  = a.x*b.x + a.y*b.y + a.z*b.z + a.w*b.w;
#pragma unroll
    for (int off = 32; off > 0; off >>= 1) {
        ssi += __shfl_xor(ssi, off);
        ssj += __shfl_xor(ssj, off);
        dd  += __shfl_xor(dd,  off);
    }
    const float invi = rsqrtf(ssi) * SQK;   // fold sqrt(2*log2e) into each side
    const float invj = rsqrtf(ssj) * SQK;

    half4v ha, hb;
    ha.x = (_Float16)(a.x * invi); ha.y = (_Float16)(a.y * invi);
    ha.z = (_Float16)(a.z * invi); ha.w = (_Float16)(a.w * invi);
    hb.x = (_Float16)(b.x * invj); hb.y = (_Float16)(b.y * invj);
    hb.z = (_Float16)(b.z * invj); hb.w = (_Float16)(b.w * invj);

    ((half4v*)(Z + (size_t)i * DD))[lane]        = ha;
    ((half4v*)(Z + (size_t)(BB + i) * DD))[lane] = hb;

    __shared__ float ps[4];
    if (lane == 0) ps[wave] = dd * invi * invj * (1.0f / (SQK * SQK)); // exact pos
    __syncthreads();
    if (threadIdx.x == 0)
        posPartial[blockIdx.x] = ps[0] + ps[1] + ps[2] + ps[3];
}

// ---------------- Kernel 2: fused sim-GEMM + exp + row-sum (no LDS) ----------
// Grid: NRT * NCH = 512 blocks (2/CU), 256 threads (4 waves). Each wave owns
// 64 r-rows as B-fragments held in registers for the whole K=256. A-fragments
// stream straight from global with a 1-deep register pipeline (incl. across
// c-tiles). No barriers after the prologue.
__global__ __launch_bounds__(256, 2) void nt_simexp(
    const _Float16* __restrict__ Z, float* __restrict__ rowsum)
{
    const int bid = blockIdx.x;
    const int rt = bid & (NRT - 1);
    const int ch = bid >> 5;            // NRT == 32
    const int tid = threadIdx.x;
    const int wave = tid >> 6;
    const int lane = tid & 63;
    const int lm = lane & 31;           // MFMA row/col index within 32
    const int lh = lane >> 5;           // half select

    const int rbase = rt * RT + wave * 64;  // this wave's 64 r-rows

    // B fragments: lane holds col n = lm, k = lh*8 + j (j=0..7), 16 k-steps.
    half8v bfrag[2][16];
#pragma unroll
    for (int b = 0; b < 2; ++b) {
        const _Float16* rowp = Z + (size_t)(rbase + b * 32 + lm) * DD + lh * 8;
#pragma unroll
        for (int s = 0; s < 16; ++s)
            bfrag[b][s] = *(const half8v*)(rowp + s * 16);
    }

    float ea0 = 0.f, ea1 = 0.f, eb0 = 0.f, eb1 = 0.f;
    const int cchunk = ch * CC;
    const bool blockdiag = (ch == (rt >> 1));

    // A-fragment stream: row cbase+lm, k = s*16 + lh*8 + j  -> contiguous 16B.
    const _Float16* ap = Z + (size_t)(cchunk + lm) * DD + lh * 8;
    half8v a_next = *(const half8v*)ap;     // tile 0, step 0

    for (int cs = 0; cs < CSTEPS; ++cs) {
        const int cbase = cchunk + cs * 32;
        const _Float16* p = ap + (size_t)cs * 32 * DD;

        floatx16 c0, c1;
#pragma unroll
        for (int r = 0; r < 16; ++r) { c0[r] = 0.f; c1[r] = 0.f; }

#pragma unroll
        for (int s = 0; s < 16; ++s) {
            half8v af = a_next;
            // Prefetch next step (or next tile's step 0; final iteration
            // prefetches 16KB past the chunk — always inside the 256MB ws).
            const _Float16* np = (s < 15) ? (p + (s + 1) * 16)
                                          : (p + (size_t)32 * DD);
            a_next = *(const half8v*)np;
            c0 = __builtin_amdgcn_mfma_f32_32x32x16_f16(af, bfrag[0][s], c0, 0, 0, 0);
            c1 = __builtin_amdgcn_mfma_f32_32x32x16_f16(af, bfrag[1][s], c1, 0, 0, 0);
        }

        // Epilogue: sims arrive pre-scaled by 2*log2e -> bare exp2.
        const bool m0 = blockdiag && (cbase == rbase);
        const bool m1 = blockdiag && (cbase == rbase + 32);
        if (!(m0 | m1)) {
#pragma unroll
            for (int r = 0; r < 16; r += 2) {
                ea0 += __builtin_amdgcn_exp2f(c0[r]);
                eb0 += __builtin_amdgcn_exp2f(c0[r + 1]);
                ea1 += __builtin_amdgcn_exp2f(c1[r]);
                eb1 += __builtin_amdgcn_exp2f(c1[r + 1]);
            }
        } else {
#pragma unroll
            for (int r = 0; r < 16; ++r) {
                const int mrow = (r & 3) + 8 * (r >> 2) + 4 * lh; // MFMA C row
                float e0 = __builtin_amdgcn_exp2f(c0[r]);
                float e1 = __builtin_amdgcn_exp2f(c1[r]);
                if (m0 && (mrow == lm)) e0 = 0.f;
                if (m1 && (mrow == lm)) e1 = 0.f;
                if (r & 1) { eb0 += e0; eb1 += e1; }
                else       { ea0 += e0; ea1 += e1; }
            }
        }
    }

    ea0 += eb0; ea1 += eb1;
    // Column (== row, symmetry) totals: combine the two lane-halves.
    ea0 += __shfl_xor(ea0, 32);
    ea1 += __shfl_xor(ea1, 32);
    if (lane < 32) {
        atomicAdd(&rowsum[rbase + lm], ea0);
        atomicAdd(&rowsum[rbase + 32 + lm], ea1);
    }
}

// ---------------- Kernel 3: finalize ----------------------------------------
__global__ __launch_bounds__(256) void nt_finalize(
    const float* __restrict__ rowsum, const float* __restrict__ posPartial,
    float* __restrict__ out)
{
    const int tid = threadIdx.x;
    float acc = 0.f;
#pragma unroll
    for (int it = 0; it < NN / 256; ++it)
        acc += __builtin_amdgcn_logf(rowsum[tid + it * 256]);   // log2
    float pacc = 0.f;
#pragma unroll
    for (int it = 0; it < 4; ++it)
        pacc += posPartial[tid + it * 256];

#pragma unroll
    for (int off = 32; off > 0; off >>= 1) {
        acc  += __shfl_xor(acc,  off);
        pacc += __shfl_xor(pacc, off);
    }
    __shared__ float sa[4], sp[4];
    const int wave = tid >> 6;
    if ((tid & 63) == 0) { sa[wave] = acc; sp[wave] = pacc; }
    __syncthreads();
    if (tid == 0) {
        const float lntot = (sa[0] + sa[1] + sa[2] + sa[3]) * 0.6931471805599453f;
        const float ptot  = sp[0] + sp[1] + sp[2] + sp[3];
        out[0] = (lntot - 4.0f * ptot) * (1.0f / (float)NN);
    }
}

// ---------------- Launch ------------------------------------------------------
extern "C" void kernel_launch(void* const* d_in, const int* in_sizes, int n_in,
                              void* d_out, int out_size, void* d_ws, size_t ws_size,
                              hipStream_t stream) {
    const float* zi = (const float*)d_in[0];
    const float* zj = (const float*)d_in[1];
    float* out = (float*)d_out;

    _Float16* Z = (_Float16*)d_ws;                                  // 4 MB
    float* rowsum = (float*)((char*)d_ws + (size_t)NN * DD * 2);    // 32 KB
    float* posPartial = rowsum + NN;                                // 4 KB

    nt_normalize<<<BB / 4, 256, 0, stream>>>(zi, zj, Z, posPartial, rowsum);
    nt_simexp<<<NRT * NCH, 256, 0, stream>>>((const _Float16*)Z, rowsum);
    nt_finalize<<<1, 256, 0, stream>>>(rowsum, posPartial, out);
}

// Round 4
// 98.003 us; speedup vs baseline: 1.3209x; 1.3209x over previous
//
#include <hip/hip_runtime.h>
#include <hip/hip_bf16.h>

// NT-Xent (SimCLR) loss, B=4096, D=256, N=8192, T=0.5.
// loss = [ sum_i log(sum_{j!=i} exp(sim_ij * 2)) - 4 * sum_{i<B} pos_i ] / N
// sim symmetric => row sums computed as column sums of MFMA tiles (per-lane).
//
// Z is stored pre-scaled by sqrt(2*log2(e)) so the MFMA emits sim*2*log2(e)
// directly (epilogue = bare exp2). pos uses the exact fp32 path in normalize.
// GEMM: coalesced global->reg->LDS staging (R3 lesson: direct global A-frag
// loads are 512B-strided across lanes = uncoalesced disaster), XOR-swizzled
// LDS, double-buffered with ONE barrier per 32-row c-tile.

constexpr int BB = 4096;     // batch
constexpr int NN = 8192;     // 2*batch
constexpr int DD = 256;      // feature dim
constexpr int RT = 256;      // r-rows per block
constexpr int CC = 512;      // c-columns per block chunk
constexpr int NRT = NN / RT; // 32 row tiles
constexpr int NCH = NN / CC; // 16 column chunks
constexpr int CSTEPS = CC / 32;

typedef _Float16 half4v __attribute__((ext_vector_type(4)));
typedef _Float16 half8v __attribute__((ext_vector_type(8)));
typedef float floatx16 __attribute__((ext_vector_type(16)));

// sqrt(2*log2(e)) : each side of the dot product carries one factor.
#define SQK 1.69864414f

// ---------------- Kernel 1: normalize rows -> f16 (pre-scaled), pos, zero ----
__global__ __launch_bounds__(256) void nt_normalize(
    const float* __restrict__ zi, const float* __restrict__ zj,
    _Float16* __restrict__ Z, float* __restrict__ posPartial,
    float* __restrict__ rowsum)
{
    const int lane = threadIdx.x & 63;
    const int wave = threadIdx.x >> 6;
    const int i = blockIdx.x * 4 + wave;   // pair index, < BB

    // Zero rowsum (8192 floats) with the first 32 blocks (stream-ordered
    // before simexp, so no race).
    if (blockIdx.x < 32) rowsum[blockIdx.x * 256 + threadIdx.x] = 0.f;

    const float4 a = ((const float4*)(zi + (size_t)i * DD))[lane];
    const float4 b = ((const float4*)(zj + (size_t)i * DD))[lane];

    float ssi = a.x*a.x + a.y*a.y + a.z*a.z + a.w*a.w;
    float ssj = b.x*b.x + b.y*b.y + b.z*b.z + b.w*b.w;
    float dd  = a.x*b.x + a.y*b.y + a.z*b.z + a.w*b.w;
#pragma unroll
    for (int off = 32; off > 0; off >>= 1) {
        ssi += __shfl_xor(ssi, off);
        ssj += __shfl_xor(ssj, off);
        dd  += __shfl_xor(dd,  off);
    }
    const float invi = rsqrtf(ssi) * SQK;   // fold sqrt(2*log2e) into each side
    const float invj = rsqrtf(ssj) * SQK;

    half4v ha, hb;
    ha.x = (_Float16)(a.x * invi); ha.y = (_Float16)(a.y * invi);
    ha.z = (_Float16)(a.z * invi); ha.w = (_Float16)(a.w * invi);
    hb.x = (_Float16)(b.x * invj); hb.y = (_Float16)(b.y * invj);
    hb.z = (_Float16)(b.z * invj); hb.w = (_Float16)(b.w * invj);

    ((half4v*)(Z + (size_t)i * DD))[lane]        = ha;
    ((half4v*)(Z + (size_t)(BB + i) * DD))[lane] = hb;

    __shared__ float ps[4];
    if (lane == 0) ps[wave] = dd * invi * invj * (1.0f / (SQK * SQK)); // exact pos
    __syncthreads();
    if (threadIdx.x == 0)
        posPartial[blockIdx.x] = ps[0] + ps[1] + ps[2] + ps[3];
}

// ---------------- Kernel 2: fused sim-GEMM + exp + row-sum -------------------
// Grid: NRT * NCH = 512 blocks (2/CU), 256 threads (4 waves). Each wave owns
// 64 r-rows (2 B-fragment sets held in registers across whole K=256). c-tiles
// of 32 rows staged coalesced into double-buffered LDS; ONE barrier per tile.
// Within a barrier interval every wave reads only lds[cs&1] and writes only
// lds[(cs+1)&1], so a single sync is sufficient.
__global__ __launch_bounds__(256, 2) void nt_simexp(
    const _Float16* __restrict__ Z, float* __restrict__ rowsum)
{
    __shared__ _Float16 lds[2][32 * DD];   // 2 x 16 KB, 16B-granule swizzled

    const int bid = blockIdx.x;
    const int rt = bid & (NRT - 1);
    const int ch = bid >> 5;            // NRT == 32
    const int tid = threadIdx.x;
    const int wave = tid >> 6;
    const int lane = tid & 63;
    const int lm = lane & 31;           // MFMA row/col index within 32
    const int lh = lane >> 5;           // half select

    const int rbase = rt * RT + wave * 64;  // this wave's 64 r-rows

    // B fragments: lane holds col n = lm, k = lh*8 + j (j=0..7), 16 k-steps.
    half8v bfrag[2][16];
#pragma unroll
    for (int b = 0; b < 2; ++b) {
        const _Float16* rowp = Z + (size_t)(rbase + b * 32 + lm) * DD + lh * 8;
#pragma unroll
        for (int s = 0; s < 16; ++s)
            bfrag[b][s] = *(const half8v*)(rowp + s * 16);
    }

    // Staging granule coords (4 granules of 16B per thread per tile).
    const int g_c0 = tid >> 5;          // c row for it=0
    const int g_kc = tid & 31;
    const int cchunk = ch * CC;

    half8v pre[4];
    auto loadTile = [&](int cs) {
#pragma unroll
        for (int it = 0; it < 4; ++it) {
            const int c = g_c0 + it * 8;
            pre[it] = *(const half8v*)(Z + (size_t)(cchunk + cs * 32 + c) * DD + g_kc * 8);
        }
    };
    auto storeTile = [&](int buf) {
#pragma unroll
        for (int it = 0; it < 4; ++it) {
            const int c = g_c0 + it * 8;
            *(half8v*)(&lds[buf][c * DD + (g_kc ^ (c & 7)) * 8]) = pre[it];
        }
    };

    float ea0 = 0.f, ea1 = 0.f, eb0 = 0.f, eb1 = 0.f;
    const bool blockdiag = (ch == (rt >> 1));

    loadTile(0);
    storeTile(0);

    for (int cs = 0; cs < CSTEPS; ++cs) {
        const int cbase = cchunk + cs * 32;

        __syncthreads();                      // lds[cs&1] ready for everyone
        if (cs + 1 < CSTEPS) loadTile(cs + 1);  // issue globals; consumed at end

        floatx16 c0, c1;
#pragma unroll
        for (int r = 0; r < 16; ++r) { c0[r] = 0.f; c1[r] = 0.f; }

        const _Float16* abuf = lds[cs & 1];
#pragma unroll
        for (int s = 0; s < 16; ++s) {
            // A fragment: lane holds row m = lm, k = lh*8 + j; granule 2s+lh.
            const int phys = (2 * s + lh) ^ (lm & 7);
            half8v af = *(const half8v*)(&abuf[lm * DD + phys * 8]);
            c0 = __builtin_amdgcn_mfma_f32_32x32x16_f16(af, bfrag[0][s], c0, 0, 0, 0);
            c1 = __builtin_amdgcn_mfma_f32_32x32x16_f16(af, bfrag[1][s], c1, 0, 0, 0);
        }

        // Epilogue: sims arrive pre-scaled by 2*log2e -> bare exp2.
        const bool m0 = blockdiag && (cbase == rbase);
        const bool m1 = blockdiag && (cbase == rbase + 32);
        if (!(m0 | m1)) {
#pragma unroll
            for (int r = 0; r < 16; r += 2) {
                ea0 += __builtin_amdgcn_exp2f(c0[r]);
                eb0 += __builtin_amdgcn_exp2f(c0[r + 1]);
                ea1 += __builtin_amdgcn_exp2f(c1[r]);
                eb1 += __builtin_amdgcn_exp2f(c1[r + 1]);
            }
        } else {
#pragma unroll
            for (int r = 0; r < 16; ++r) {
                const int mrow = (r & 3) + 8 * (r >> 2) + 4 * lh; // MFMA C row
                float e0 = __builtin_amdgcn_exp2f(c0[r]);
                float e1 = __builtin_amdgcn_exp2f(c1[r]);
                if (m0 && (mrow == lm)) e0 = 0.f;
                if (m1 && (mrow == lm)) e1 = 0.f;
                if (r & 1) { eb0 += e0; eb1 += e1; }
                else       { ea0 += e0; ea1 += e1; }
            }
        }

        if (cs + 1 < CSTEPS) storeTile((cs + 1) & 1);  // other buffer: no race
    }

    ea0 += eb0; ea1 += eb1;
    // Column (== row, symmetry) totals: combine the two lane-halves.
    ea0 += __shfl_xor(ea0, 32);
    ea1 += __shfl_xor(ea1, 32);
    if (lane < 32) {
        atomicAdd(&rowsum[rbase + lm], ea0);
        atomicAdd(&rowsum[rbase + 32 + lm], ea1);
    }
}

// ---------------- Kernel 3: finalize ----------------------------------------
__global__ __launch_bounds__(256) void nt_finalize(
    const float* __restrict__ rowsum, const float* __restrict__ posPartial,
    float* __restrict__ out)
{
    const int tid = threadIdx.x;
    float acc = 0.f;
#pragma unroll
    for (int it = 0; it < NN / 256; ++it)
        acc += __builtin_amdgcn_logf(rowsum[tid + it * 256]);   // log2
    float pacc = 0.f;
#pragma unroll
    for (int it = 0; it < 4; ++it)
        pacc += posPartial[tid + it * 256];

#pragma unroll
    for (int off = 32; off > 0; off >>= 1) {
        acc  += __shfl_xor(acc,  off);
        pacc += __shfl_xor(pacc, off);
    }
    __shared__ float sa[4], sp[4];
    const int wave = tid >> 6;
    if ((tid & 63) == 0) { sa[wave] = acc; sp[wave] = pacc; }
    __syncthreads();
    if (tid == 0) {
        const float lntot = (sa[0] + sa[1] + sa[2] + sa[3]) * 0.6931471805599453f;
        const float ptot  = sp[0] + sp[1] + sp[2] + sp[3];
        out[0] = (lntot - 4.0f * ptot) * (1.0f / (float)NN);
    }
}

// ---------------- Launch ------------------------------------------------------
extern "C" void kernel_launch(void* const* d_in, const int* in_sizes, int n_in,
                              void* d_out, int out_size, void* d_ws, size_t ws_size,
                              hipStream_t stream) {
    const float* zi = (const float*)d_in[0];
    const float* zj = (const float*)d_in[1];
    float* out = (float*)d_out;

    _Float16* Z = (_Float16*)d_ws;                                  // 4 MB
    float* rowsum = (float*)((char*)d_ws + (size_t)NN * DD * 2);    // 32 KB
    float* posPartial = rowsum + NN;                                // 4 KB

    nt_normalize<<<BB / 4, 256, 0, stream>>>(zi, zj, Z, posPartial, rowsum);
    nt_simexp<<<NRT * NCH, 256, 0, stream>>>((const _Float16*)Z, rowsum);
    nt_finalize<<<1, 256, 0, stream>>>(rowsum, posPartial, out);
}